// Round 1
// baseline (324.879 us; speedup 1.0000x reference)
//
#include <hip/hip_runtime.h>
#include <math.h>

#define SEQ 4096
#define DMODEL 1024
#define NHEADS 16
#define HDIM 64

typedef __bf16 v8bf __attribute__((ext_vector_type(8)));
typedef float f32x4 __attribute__((ext_vector_type(4)));

__device__ __forceinline__ unsigned short f2bf(float f) {
    union { float f; unsigned int u; } v; v.f = f;
    unsigned int u = v.u;
    return (unsigned short)((u + 0x7fffu + ((u >> 16) & 1u)) >> 16);
}

// ---------------------------------------------------------------------------
// Kernel 1: projection GEMM  C = X @ W^T  (4096x1024 @ 1024x1024^T), bf16 MFMA.
//   z=0: qh[h][s][64] bf16 with RoPE
//   z=1: kh[h][s][64] bf16 with RoPE
//   z=2: vht[h][64][s] bf16 transposed (PV B-operand becomes contiguous)
// 128x128 tile, BK=32, 4 waves (2x2), each wave 64x64 (4x4 frags of 16x16).
// fp32 global -> regs -> bf16 swizzled LDS (reg staging doubles as the cast).
// LDS swizzle: 16B-block cb' = cb ^ ((row>>1)&3)  -> frag ds_read_b128 ~2-way.
// ---------------------------------------------------------------------------
__global__ __launch_bounds__(256) void proj_rope_kernel(
    const float* __restrict__ Xq, const float* __restrict__ Xk, const float* __restrict__ Xv,
    const float* __restrict__ Wq, const float* __restrict__ Wk, const float* __restrict__ Wv,
    unsigned short* __restrict__ qh, unsigned short* __restrict__ kh,
    unsigned short* __restrict__ vht)
{
    const int tz = blockIdx.z;
    const float* __restrict__ X = (tz == 0) ? Xq : (tz == 1) ? Xk : Xv;
    const float* __restrict__ W = (tz == 0) ? Wq : (tz == 1) ? Wk : Wv;

    const int tid = threadIdx.x;
    const int lane = tid & 63;
    const int wid = tid >> 6;
    const int l15 = lane & 15;
    const int l4 = lane >> 4;
    const int wr = wid >> 1, wc = wid & 1;

    const int m0 = blockIdx.x * 128;
    const int n0 = blockIdx.y * 128;

    __shared__ __align__(16) unsigned short Ab[128 * 32];
    __shared__ __align__(16) unsigned short Bb[128 * 32];

    float4 ra[4], rb[4];
    f32x4 acc[4][4] = {};

    // prologue: k-tile 0 -> regs
    #pragma unroll
    for (int c = 0; c < 4; ++c) {
        int i = tid + (c << 8);
        int row = i >> 3;
        int c4 = (i & 7) << 2;
        ra[c] = *reinterpret_cast<const float4*>(X + (size_t)(m0 + row) * DMODEL + c4);
        rb[c] = *reinterpret_cast<const float4*>(W + (size_t)(n0 + row) * DMODEL + c4);
    }

    for (int kt = 0; kt < 32; ++kt) {
        if (kt > 0) __syncthreads();
        // regs -> bf16 swizzled LDS
        #pragma unroll
        for (int c = 0; c < 4; ++c) {
            int i = tid + (c << 8);
            int row = i >> 3;
            int c4 = (i & 7) << 2;                      // col in fp32 elems
            int byte = row * 64 + (((c4 >> 3) ^ ((row >> 1) & 3)) << 4) + ((c4 << 1) & 15);
            uint2 pa, pb;
            pa.x = (unsigned)f2bf(ra[c].x) | ((unsigned)f2bf(ra[c].y) << 16);
            pa.y = (unsigned)f2bf(ra[c].z) | ((unsigned)f2bf(ra[c].w) << 16);
            pb.x = (unsigned)f2bf(rb[c].x) | ((unsigned)f2bf(rb[c].y) << 16);
            pb.y = (unsigned)f2bf(rb[c].z) | ((unsigned)f2bf(rb[c].w) << 16);
            *reinterpret_cast<uint2*>(reinterpret_cast<char*>(Ab) + byte) = pa;
            *reinterpret_cast<uint2*>(reinterpret_cast<char*>(Bb) + byte) = pb;
        }
        // prefetch next k-tile into regs (in flight during MFMA)
        if (kt < 31) {
            int k0 = (kt + 1) << 5;
            #pragma unroll
            for (int c = 0; c < 4; ++c) {
                int i = tid + (c << 8);
                int row = i >> 3;
                int c4 = (i & 7) << 2;
                ra[c] = *reinterpret_cast<const float4*>(X + (size_t)(m0 + row) * DMODEL + k0 + c4);
                rb[c] = *reinterpret_cast<const float4*>(W + (size_t)(n0 + row) * DMODEL + k0 + c4);
            }
        }
        __syncthreads();

        v8bf af[4], bfr[4];
        #pragma unroll
        for (int mi = 0; mi < 4; ++mi) {
            int row = wr * 64 + mi * 16 + l15;
            int byte = row * 64 + ((l4 ^ ((row >> 1) & 3)) << 4);
            af[mi] = *reinterpret_cast<const v8bf*>(reinterpret_cast<const char*>(Ab) + byte);
        }
        #pragma unroll
        for (int ni = 0; ni < 4; ++ni) {
            int row = wc * 64 + ni * 16 + l15;
            int byte = row * 64 + ((l4 ^ ((row >> 1) & 3)) << 4);
            bfr[ni] = *reinterpret_cast<const v8bf*>(reinterpret_cast<const char*>(Bb) + byte);
        }
        #pragma unroll
        for (int mi = 0; mi < 4; ++mi)
            #pragma unroll
            for (int ni = 0; ni < 4; ++ni)
                acc[mi][ni] = __builtin_amdgcn_mfma_f32_16x16x32_bf16(af[mi], bfr[ni], acc[mi][ni], 0, 0, 0);
    }

    // epilogue: C/D layout col=lane&15, row=(lane>>4)*4+r  [guide m89]
    const int h = (n0 >> 6) + wc;       // wave's 64 cols = exactly one head
    const int mbase = m0 + wr * 64;
    if (tz == 2) {
        // transposed V: vht[h][d][m]; lane's 4 r-values are contiguous in m
        unsigned short* base = vht + (size_t)h * HDIM * SEQ;
        #pragma unroll
        for (int mi = 0; mi < 4; ++mi) {
            #pragma unroll
            for (int ni = 0; ni < 4; ++ni) {
                int d = ni * 16 + l15;
                int m = mbase + mi * 16 + l4 * 4;
                uint2 pk;
                pk.x = (unsigned)f2bf(acc[mi][ni][0]) | ((unsigned)f2bf(acc[mi][ni][1]) << 16);
                pk.y = (unsigned)f2bf(acc[mi][ni][2]) | ((unsigned)f2bf(acc[mi][ni][3]) << 16);
                *reinterpret_cast<uint2*>(base + (size_t)d * SEQ + m) = pk;
            }
        }
    } else {
        // RoPE: pair (j, j+32) = fragments ni and ni+2, same lane
        unsigned short* base = ((tz == 0) ? qh : kh) + (size_t)h * SEQ * HDIM;
        #pragma unroll
        for (int ni = 0; ni < 2; ++ni) {
            int j = ni * 16 + l15;                          // 0..31
            float invf = expf(-(float)j * 0.28782313662425574f);  // ln(10000)/32
            #pragma unroll
            for (int mi = 0; mi < 4; ++mi) {
                #pragma unroll
                for (int r = 0; r < 4; ++r) {
                    int m = mbase + mi * 16 + l4 * 4 + r;
                    float ang = (float)m * invf;
                    float sn, cs;
                    sincosf(ang, &sn, &cs);
                    float x1 = acc[mi][ni][r];
                    float x2 = acc[mi][ni + 2][r];
                    base[(size_t)m * HDIM + j]      = f2bf(x1 * cs - x2 * sn);
                    base[(size_t)m * HDIM + j + 32] = f2bf(x1 * sn + x2 * cs);
                }
            }
        }
    }
}

// ---------------------------------------------------------------------------
// Kernel 2: causal flash attention. Block = (qb, h), 4 waves x 32 q-rows
// (QBLK=128), KVBLK=64. K/V tiles reg-prefetched then staged to XOR-swizzled
// LDS (byte ^= (row&7)<<4 on 128B rows -> conflict-free b128 frag reads).
// Online softmax in exp2 domain; P via swizzled per-wave LDS round-trip.
// Causal: only nt = 2*qb+2 tiles processed; per-element mask on diagonal.
// ---------------------------------------------------------------------------
__global__ __launch_bounds__(256) void attn_kernel(
    const unsigned short* __restrict__ qh, const unsigned short* __restrict__ kh,
    const unsigned short* __restrict__ vht, float* __restrict__ out)
{
    const int tid = threadIdx.x;
    const int lane = tid & 63;
    const int wid = tid >> 6;
    const int l15 = lane & 15;
    const int l4 = lane >> 4;
    const int h = blockIdx.y;
    const int qb = (int)(gridDim.x - 1) - (int)blockIdx.x;   // big blocks first
    const int q0 = qb * 128;
    const int qr0 = q0 + wid * 32;

    __shared__ __align__(16) unsigned short Kt[64 * 64];
    __shared__ __align__(16) unsigned short Vt[64 * 64];
    __shared__ __align__(16) unsigned short Pl[4][32 * 64];

    const unsigned short* __restrict__ khh = kh + (size_t)h * SEQ * HDIM;
    const unsigned short* __restrict__ vhh = vht + (size_t)h * HDIM * SEQ;

    // Q fragments (held in registers for the whole block)
    v8bf qf[2][2];
    {
        const unsigned short* qhh = qh + (size_t)h * SEQ * HDIM;
        #pragma unroll
        for (int ms = 0; ms < 2; ++ms)
            #pragma unroll
            for (int ks = 0; ks < 2; ++ks)
                qf[ms][ks] = *reinterpret_cast<const v8bf*>(
                    qhh + (size_t)(qr0 + ms * 16 + l15) * HDIM + ks * 32 + l4 * 8);
    }

    f32x4 oacc[2][4] = {};
    float mst[2][4], lst[2][4];
    #pragma unroll
    for (int ms = 0; ms < 2; ++ms)
        #pragma unroll
        for (int r = 0; r < 4; ++r) { mst[ms][r] = -INFINITY; lst[ms][r] = 0.0f; }

    const int nt = (q0 + 128) / 64;
    uint4 kreg[2], vreg[2];

    // prologue loads, tile 0
    #pragma unroll
    for (int c = 0; c < 2; ++c) {
        int i = tid + (c << 8);
        int row = i >> 3, cb = i & 7;
        kreg[c] = *reinterpret_cast<const uint4*>(khh + (size_t)row * HDIM + cb * 8);
        vreg[c] = *reinterpret_cast<const uint4*>(vhh + (size_t)row * SEQ + cb * 8);
    }

    for (int t = 0; t < nt; ++t) {
        if (t > 0) __syncthreads();
        // regs -> swizzled LDS
        #pragma unroll
        for (int c = 0; c < 2; ++c) {
            int i = tid + (c << 8);
            int row = i >> 3, cb = i & 7;
            int byte = row * 128 + ((cb ^ (row & 7)) << 4);
            *reinterpret_cast<uint4*>(reinterpret_cast<char*>(Kt) + byte) = kreg[c];
            *reinterpret_cast<uint4*>(reinterpret_cast<char*>(Vt) + byte) = vreg[c];
        }
        // prefetch next tile into regs
        if (t + 1 < nt) {
            int kv0n = (t + 1) * 64;
            #pragma unroll
            for (int c = 0; c < 2; ++c) {
                int i = tid + (c << 8);
                int row = i >> 3, cb = i & 7;
                kreg[c] = *reinterpret_cast<const uint4*>(khh + (size_t)(kv0n + row) * HDIM + cb * 8);
                vreg[c] = *reinterpret_cast<const uint4*>(vhh + (size_t)row * SEQ + kv0n + cb * 8);
            }
        }
        __syncthreads();

        // ---- S = Q K^T  (per wave: 32x64) ----
        f32x4 sacc[2][4] = {};
        #pragma unroll
        for (int ks = 0; ks < 2; ++ks) {
            v8bf kf[4];
            #pragma unroll
            for (int ns = 0; ns < 4; ++ns) {
                int row = ns * 16 + l15;
                int byte = row * 128 + (((ks * 4 + l4) ^ (row & 7)) << 4);
                kf[ns] = *reinterpret_cast<const v8bf*>(reinterpret_cast<const char*>(Kt) + byte);
            }
            #pragma unroll
            for (int ms = 0; ms < 2; ++ms)
                #pragma unroll
                for (int ns = 0; ns < 4; ++ns)
                    sacc[ms][ns] = __builtin_amdgcn_mfma_f32_16x16x32_bf16(qf[ms][ks], kf[ns], sacc[ms][ns], 0, 0, 0);
        }

        // ---- scale (exp2 domain) + causal mask ----
        const float SC = 0.18033688011112042f;   // 0.125 * log2(e)
        const int kv0 = t * 64;
        #pragma unroll
        for (int ms = 0; ms < 2; ++ms) {
            #pragma unroll
            for (int ns = 0; ns < 4; ++ns) {
                int kv = kv0 + ns * 16 + l15;
                #pragma unroll
                for (int r = 0; r < 4; ++r) {
                    int qrow = qr0 + ms * 16 + l4 * 4 + r;
                    float vv = sacc[ms][ns][r] * SC;
                    sacc[ms][ns][r] = (kv <= qrow) ? vv : -INFINITY;
                }
            }
        }

        // ---- online softmax (row max cross-lane; l-sum kept lane-partial) ----
        #pragma unroll
        for (int ms = 0; ms < 2; ++ms) {
            #pragma unroll
            for (int r = 0; r < 4; ++r) {
                float mx = fmaxf(fmaxf(sacc[ms][0][r], sacc[ms][1][r]),
                                 fmaxf(sacc[ms][2][r], sacc[ms][3][r]));
                #pragma unroll
                for (int d = 1; d < 16; d <<= 1) mx = fmaxf(mx, __shfl_xor(mx, d));
                float mnew = fmaxf(mst[ms][r], mx);
                float sc = exp2f(mst[ms][r] - mnew);
                float psum = 0.0f;
                #pragma unroll
                for (int ns = 0; ns < 4; ++ns) {
                    float p = exp2f(sacc[ms][ns][r] - mnew);
                    sacc[ms][ns][r] = p;
                    psum += p;
                }
                lst[ms][r] = lst[ms][r] * sc + psum;
                mst[ms][r] = mnew;
                #pragma unroll
                for (int dd = 0; dd < 4; ++dd) oacc[ms][dd][r] *= sc;
            }
        }

        // ---- P -> wave-private swizzled LDS (bf16) ----
        unsigned short* pw = Pl[wid];
        #pragma unroll
        for (int ms = 0; ms < 2; ++ms)
            #pragma unroll
            for (int ns = 0; ns < 4; ++ns)
                #pragma unroll
                for (int r = 0; r < 4; ++r) {
                    int row = ms * 16 + l4 * 4 + r;
                    int col = ns * 16 + l15;
                    int byte = row * 128 + ((col * 2) ^ ((row & 7) << 4));
                    *reinterpret_cast<unsigned short*>(reinterpret_cast<char*>(pw) + byte)
                        = f2bf(sacc[ms][ns][r]);
                }

        // ---- O += P V ----
        #pragma unroll
        for (int ks = 0; ks < 2; ++ks) {
            v8bf pf[2], vf[4];
            #pragma unroll
            for (int ms = 0; ms < 2; ++ms) {
                int row = ms * 16 + l15;
                int byte = row * 128 + ((((ks * 4 + l4)) ^ (row & 7)) << 4);
                pf[ms] = *reinterpret_cast<const v8bf*>(reinterpret_cast<const char*>(pw) + byte);
            }
            #pragma unroll
            for (int dd = 0; dd < 4; ++dd) {
                int row = dd * 16 + l15;
                int byte = row * 128 + (((ks * 4 + l4) ^ (row & 7)) << 4);
                vf[dd] = *reinterpret_cast<const v8bf*>(reinterpret_cast<const char*>(Vt) + byte);
            }
            #pragma unroll
            for (int ms = 0; ms < 2; ++ms)
                #pragma unroll
                for (int dd = 0; dd < 4; ++dd)
                    oacc[ms][dd] = __builtin_amdgcn_mfma_f32_16x16x32_bf16(pf[ms], vf[dd], oacc[ms][dd], 0, 0, 0);
        }
    }

    // ---- finalize: cross-lane l reduce, O/l, store fp32 ----
    #pragma unroll
    for (int ms = 0; ms < 2; ++ms) {
        float inv[4];
        #pragma unroll
        for (int r = 0; r < 4; ++r) {
            float s = lst[ms][r];
            #pragma unroll
            for (int d = 1; d < 16; d <<= 1) s += __shfl_xor(s, d);
            inv[r] = 1.0f / s;
        }
        #pragma unroll
        for (int dd = 0; dd < 4; ++dd)
            #pragma unroll
            for (int r = 0; r < 4; ++r) {
                int qrow = qr0 + ms * 16 + l4 * 4 + r;
                out[(size_t)qrow * DMODEL + h * HDIM + dd * 16 + l15] = oacc[ms][dd][r] * inv[r];
            }
    }
}

extern "C" void kernel_launch(void* const* d_in, const int* in_sizes, int n_in,
                              void* d_out, int out_size, void* d_ws, size_t ws_size,
                              hipStream_t stream) {
    (void)in_sizes; (void)n_in; (void)out_size; (void)ws_size;
    const float* q  = (const float*)d_in[0];
    const float* k  = (const float*)d_in[1];
    const float* v  = (const float*)d_in[2];
    // d_in[3] = mask: tril(ones) -> causal, applied analytically
    const float* Wq = (const float*)d_in[4];
    const float* Wk = (const float*)d_in[5];
    const float* Wv = (const float*)d_in[6];

    unsigned short* qh  = (unsigned short*)d_ws;                 // 8 MB
    unsigned short* kh  = qh + (size_t)NHEADS * SEQ * HDIM;      // 8 MB
    unsigned short* vht = kh + (size_t)NHEADS * SEQ * HDIM;      // 8 MB
    float* out = (float*)d_out;

    dim3 g1(SEQ / 128, DMODEL / 128, 3);
    proj_rope_kernel<<<g1, 256, 0, stream>>>(q, k, v, Wq, Wk, Wv, qh, kh, vht);

    dim3 g2(SEQ / 128, NHEADS, 1);
    attn_kernel<<<g2, 256, 0, stream>>>(qh, kh, vht, out);
}

// Round 2
// 225.579 us; speedup vs baseline: 1.4402x; 1.4402x over previous
//
#include <hip/hip_runtime.h>
#include <math.h>

#define SEQ 4096
#define DMODEL 1024
#define NHEADS 16
#define HDIM 64

typedef __bf16 v8bf __attribute__((ext_vector_type(8)));
typedef float f32x4 __attribute__((ext_vector_type(4)));
typedef float f32x16 __attribute__((ext_vector_type(16)));
typedef int i32x2 __attribute__((ext_vector_type(2)));
typedef int i32x4 __attribute__((ext_vector_type(4)));

__device__ __forceinline__ unsigned short f2bf(float f) {
    union { float f; unsigned int u; } v; v.f = f;
    unsigned int u = v.u;
    return (unsigned short)((u + 0x7fffu + ((u >> 16) & 1u)) >> 16);
}

__device__ __forceinline__ int cvtpk(float lo, float hi) {
    int r;
    asm("v_cvt_pk_bf16_f32 %0, %1, %2" : "=v"(r) : "v"(lo), "v"(hi));
    return r;
}

// ---------------------------------------------------------------------------
// Kernel 1: projection GEMM  C = X @ W^T  (4096x1024 @ 1024x1024^T), bf16 MFMA.
//   z=0: qh[h][s][64] bf16 with RoPE
//   z=1: kh[h][s][64] bf16 with RoPE
//   z=2: vht[h][64][s] bf16 transposed (PV A-operand becomes contiguous)
// (unchanged from round 1: ~42 us, ~614 TF)
// ---------------------------------------------------------------------------
__global__ __launch_bounds__(256) void proj_rope_kernel(
    const float* __restrict__ Xq, const float* __restrict__ Xk, const float* __restrict__ Xv,
    const float* __restrict__ Wq, const float* __restrict__ Wk, const float* __restrict__ Wv,
    unsigned short* __restrict__ qh, unsigned short* __restrict__ kh,
    unsigned short* __restrict__ vht)
{
    const int tz = blockIdx.z;
    const float* __restrict__ X = (tz == 0) ? Xq : (tz == 1) ? Xk : Xv;
    const float* __restrict__ W = (tz == 0) ? Wq : (tz == 1) ? Wk : Wv;

    const int tid = threadIdx.x;
    const int lane = tid & 63;
    const int wid = tid >> 6;
    const int l15 = lane & 15;
    const int l4 = lane >> 4;
    const int wr = wid >> 1, wc = wid & 1;

    const int m0 = blockIdx.x * 128;
    const int n0 = blockIdx.y * 128;

    __shared__ __align__(16) unsigned short Ab[128 * 32];
    __shared__ __align__(16) unsigned short Bb[128 * 32];

    float4 ra[4], rb[4];
    f32x4 acc[4][4] = {};

    #pragma unroll
    for (int c = 0; c < 4; ++c) {
        int i = tid + (c << 8);
        int row = i >> 3;
        int c4 = (i & 7) << 2;
        ra[c] = *reinterpret_cast<const float4*>(X + (size_t)(m0 + row) * DMODEL + c4);
        rb[c] = *reinterpret_cast<const float4*>(W + (size_t)(n0 + row) * DMODEL + c4);
    }

    for (int kt = 0; kt < 32; ++kt) {
        if (kt > 0) __syncthreads();
        #pragma unroll
        for (int c = 0; c < 4; ++c) {
            int i = tid + (c << 8);
            int row = i >> 3;
            int c4 = (i & 7) << 2;
            int byte = row * 64 + (((c4 >> 3) ^ ((row >> 1) & 3)) << 4) + ((c4 << 1) & 15);
            uint2 pa, pb;
            pa.x = (unsigned)f2bf(ra[c].x) | ((unsigned)f2bf(ra[c].y) << 16);
            pa.y = (unsigned)f2bf(ra[c].z) | ((unsigned)f2bf(ra[c].w) << 16);
            pb.x = (unsigned)f2bf(rb[c].x) | ((unsigned)f2bf(rb[c].y) << 16);
            pb.y = (unsigned)f2bf(rb[c].z) | ((unsigned)f2bf(rb[c].w) << 16);
            *reinterpret_cast<uint2*>(reinterpret_cast<char*>(Ab) + byte) = pa;
            *reinterpret_cast<uint2*>(reinterpret_cast<char*>(Bb) + byte) = pb;
        }
        if (kt < 31) {
            int k0 = (kt + 1) << 5;
            #pragma unroll
            for (int c = 0; c < 4; ++c) {
                int i = tid + (c << 8);
                int row = i >> 3;
                int c4 = (i & 7) << 2;
                ra[c] = *reinterpret_cast<const float4*>(X + (size_t)(m0 + row) * DMODEL + k0 + c4);
                rb[c] = *reinterpret_cast<const float4*>(W + (size_t)(n0 + row) * DMODEL + k0 + c4);
            }
        }
        __syncthreads();

        v8bf af[4], bfr[4];
        #pragma unroll
        for (int mi = 0; mi < 4; ++mi) {
            int row = wr * 64 + mi * 16 + l15;
            int byte = row * 64 + ((l4 ^ ((row >> 1) & 3)) << 4);
            af[mi] = *reinterpret_cast<const v8bf*>(reinterpret_cast<const char*>(Ab) + byte);
        }
        #pragma unroll
        for (int ni = 0; ni < 4; ++ni) {
            int row = wc * 64 + ni * 16 + l15;
            int byte = row * 64 + ((l4 ^ ((row >> 1) & 3)) << 4);
            bfr[ni] = *reinterpret_cast<const v8bf*>(reinterpret_cast<const char*>(Bb) + byte);
        }
        #pragma unroll
        for (int mi = 0; mi < 4; ++mi)
            #pragma unroll
            for (int ni = 0; ni < 4; ++ni)
                acc[mi][ni] = __builtin_amdgcn_mfma_f32_16x16x32_bf16(af[mi], bfr[ni], acc[mi][ni], 0, 0, 0);
    }

    const int h = (n0 >> 6) + wc;
    const int mbase = m0 + wr * 64;
    if (tz == 2) {
        unsigned short* base = vht + (size_t)h * HDIM * SEQ;
        #pragma unroll
        for (int mi = 0; mi < 4; ++mi) {
            #pragma unroll
            for (int ni = 0; ni < 4; ++ni) {
                int d = ni * 16 + l15;
                int m = mbase + mi * 16 + l4 * 4;
                uint2 pk;
                pk.x = (unsigned)f2bf(acc[mi][ni][0]) | ((unsigned)f2bf(acc[mi][ni][1]) << 16);
                pk.y = (unsigned)f2bf(acc[mi][ni][2]) | ((unsigned)f2bf(acc[mi][ni][3]) << 16);
                *reinterpret_cast<uint2*>(base + (size_t)d * SEQ + m) = pk;
            }
        }
    } else {
        unsigned short* base = ((tz == 0) ? qh : kh) + (size_t)h * SEQ * HDIM;
        #pragma unroll
        for (int ni = 0; ni < 2; ++ni) {
            int j = ni * 16 + l15;
            float invf = expf(-(float)j * 0.28782313662425574f);  // ln(10000)/32
            #pragma unroll
            for (int mi = 0; mi < 4; ++mi) {
                #pragma unroll
                for (int r = 0; r < 4; ++r) {
                    int m = mbase + mi * 16 + l4 * 4 + r;
                    float ang = (float)m * invf;
                    float sn, cs;
                    sincosf(ang, &sn, &cs);
                    float x1 = acc[mi][ni][r];
                    float x2 = acc[mi][ni + 2][r];
                    base[(size_t)m * HDIM + j]      = f2bf(x1 * cs - x2 * sn);
                    base[(size_t)m * HDIM + j + 32] = f2bf(x1 * sn + x2 * cs);
                }
            }
        }
    }
}

// ---------------------------------------------------------------------------
// Kernel 2: causal flash attention, swapped-QK^T 32x32 structure (guide SB/T12).
// 1 wave per block, 32 q-rows/wave, KV rounds of 64. No LDS, no barriers.
// S^T = mfma(A=K, B=Q)  -> lane owns full q-row slice (col = q = lane&31).
// Softmax in exp2 domain; row-max via in-reg tree + 1 permlane32_swap.
// P^T B-fragments via v_cvt_pk_bf16_f32 + permlane32_swap (T12).
// O^T = mfma(A=V^T, B=P^T): rescale factor & l live in-lane (col = q).
// K double-buffered in regs (prefetch next round); V issued at round start.
// Grid 2048 blocks: XCD-grouped (2 heads/XCD -> K/V L2-resident), big-qb first.
// ---------------------------------------------------------------------------
__global__ __launch_bounds__(64, 2) void attn_kernel(
    const unsigned short* __restrict__ qh, const unsigned short* __restrict__ kh,
    const unsigned short* __restrict__ vht, float* __restrict__ out)
{
    const int lane = threadIdx.x & 63;
    const int l31 = lane & 31;
    const int l5 = lane >> 5;

    const int bid = blockIdx.x;
    const int xcd = bid & 7;
    const int j = bid >> 3;                  // 0..255
    const int h = (xcd << 1) | (j >> 7);     // 2 heads per XCD
    const int qb = 127 - (j & 127);          // big blocks first
    const int q0 = qb * 32;
    const int q = q0 + l31;
    const int nt = (q0 + 32 + 63) >> 6;      // ceil((q0+32)/64) kv-rounds of 64

    const unsigned short* __restrict__ qbase = qh + ((size_t)h * SEQ + q) * HDIM + l5 * 8;
    const unsigned short* __restrict__ kbase = kh + ((size_t)h * SEQ + l31) * HDIM + l5 * 8;
    const unsigned short* __restrict__ vbase = vht + ((size_t)h * HDIM + l31) * SEQ + l5 * 8;

    // Q B-fragments: col = q = lane&31, k = d = dk*16 + l5*8 + j
    v8bf qf[4];
    #pragma unroll
    for (int dk = 0; dk < 4; ++dk)
        qf[dk] = *reinterpret_cast<const v8bf*>(qbase + dk * 16);

    f32x16 of[2] = {};                // O^T acc: col=q=l31, row=d (2 x 32-d blocks)
    float mreg = -INFINITY, lreg = 0.0f;
    const float SC = 0.18033688011112042f;   // 0.125 * log2(e)

    auto LOADK = [&](v8bf (&KB)[8], int T) {
        const unsigned short* kp = kbase + (size_t)T * 64 * HDIM;
        #pragma unroll
        for (int ns = 0; ns < 2; ++ns)
            #pragma unroll
            for (int dk = 0; dk < 4; ++dk)
                KB[ns * 4 + dk] = *reinterpret_cast<const v8bf*>(kp + ns * 32 * HDIM + dk * 16);
    };

    auto ROUND = [&](int T, v8bf (&KC)[8], v8bf (&KN)[8]) {
        const int kv0 = T * 64;
        // V^T A-fragments for this round (issued early, used after softmax)
        v8bf vf[8];
        #pragma unroll
        for (int dt = 0; dt < 2; ++dt)
            #pragma unroll
            for (int kb = 0; kb < 4; ++kb)
                vf[dt * 4 + kb] = *reinterpret_cast<const v8bf*>(
                    vbase + (size_t)dt * 32 * SEQ + kv0 + kb * 16);
        // prefetch next round's K
        if (T + 1 < nt) LOADK(KN, T + 1);

        // ---- S^T = K Q^T : st[ns] col=q=l31, row_kv = (i&3)+8*(i>>2)+4*l5 ----
        f32x16 st[2];
        #pragma unroll
        for (int ns = 0; ns < 2; ++ns) {
            f32x16 acc = {};
            #pragma unroll
            for (int dk = 0; dk < 4; ++dk)
                acc = __builtin_amdgcn_mfma_f32_32x32x16_bf16(KC[ns * 4 + dk], qf[dk], acc, 0, 0, 0);
            st[ns] = acc;
        }

        // ---- scale + causal mask ----
        const int kvb = kv0 + 4 * l5;
        #pragma unroll
        for (int ns = 0; ns < 2; ++ns)
            #pragma unroll
            for (int i = 0; i < 16; ++i) {
                int kv = kvb + ns * 32 + (i & 3) + 8 * (i >> 2);
                float vv = st[ns][i] * SC;
                st[ns][i] = (kv <= q) ? vv : -INFINITY;
            }

        // ---- row max: tree over 32 in-lane values + 1 permlane32_swap ----
        float t16[16];
        #pragma unroll
        for (int i = 0; i < 16; ++i) t16[i] = fmaxf(st[0][i], st[1][i]);
        #pragma unroll
        for (int i = 0; i < 8; ++i) t16[i] = fmaxf(t16[i], t16[i + 8]);
        #pragma unroll
        for (int i = 0; i < 4; ++i) t16[i] = fmaxf(t16[i], t16[i + 4]);
        float pmax = fmaxf(fmaxf(t16[0], t16[1]), fmaxf(t16[2], t16[3]));
        {
            i32x2 sw = __builtin_amdgcn_permlane32_swap(__float_as_int(pmax), __float_as_int(pmax), false, false);
            pmax = fmaxf(__int_as_float(sw.x), __int_as_float(sw.y));
        }
        float mnew = fmaxf(mreg, pmax);
        float sc = exp2f(mreg - mnew);
        mreg = mnew;

        // ---- exp2 + partial row-sum (4 parallel accumulators) ----
        float ps0 = 0.f, ps1 = 0.f, ps2 = 0.f, ps3 = 0.f;
        #pragma unroll
        for (int ns = 0; ns < 2; ++ns)
            #pragma unroll
            for (int i = 0; i < 16; ++i) {
                float p = exp2f(st[ns][i] - mnew);
                st[ns][i] = p;
                if ((i & 3) == 0) ps0 += p; else if ((i & 3) == 1) ps1 += p;
                else if ((i & 3) == 2) ps2 += p; else ps3 += p;
            }
        lreg = lreg * sc + ((ps0 + ps1) + (ps2 + ps3));

        // ---- rescale O^T (sc is per-q, in-lane) ----
        #pragma unroll
        for (int dt = 0; dt < 2; ++dt)
            #pragma unroll
            for (int i = 0; i < 16; ++i) of[dt][i] *= sc;

        // ---- P^T B-fragments: cvt_pk + permlane32_swap (one swap = two words) ----
        v8bf pt[4];
        #pragma unroll
        for (int kb = 0; kb < 4; ++kb) {
            int ns = kb >> 1, kp = (kb & 1) * 8;
            int A0 = cvtpk(st[ns][kp + 0], st[ns][kp + 1]);
            int A1 = cvtpk(st[ns][kp + 2], st[ns][kp + 3]);
            int B0 = cvtpk(st[ns][kp + 4], st[ns][kp + 5]);
            int B1 = cvtpk(st[ns][kp + 6], st[ns][kp + 7]);
            i32x2 s0 = __builtin_amdgcn_permlane32_swap(A0, B0, false, false);
            i32x2 s1 = __builtin_amdgcn_permlane32_swap(A1, B1, false, false);
            i32x4 u; u.x = s0.x; u.y = s1.x; u.z = s0.y; u.w = s1.y;
            v8bf p; __builtin_memcpy(&p, &u, 16);
            pt[kb] = p;
        }

        // ---- O^T += V^T P^T ----
        #pragma unroll
        for (int dt = 0; dt < 2; ++dt)
            #pragma unroll
            for (int kb = 0; kb < 4; ++kb)
                of[dt] = __builtin_amdgcn_mfma_f32_32x32x16_bf16(vf[dt * 4 + kb], pt[kb], of[dt], 0, 0, 0);
    };

    v8bf kA[8], kB[8];
    LOADK(kA, 0);
    int t = 0;
    while (true) {
        ROUND(t, kA, kB);
        if (++t == nt) break;
        ROUND(t, kB, kA);
        if (++t == nt) break;
    }

    // ---- finalize: pair-sum l across l5 halves, divide, store float4 ----
    {
        i32x2 sw = __builtin_amdgcn_permlane32_swap(__float_as_int(lreg), __float_as_int(lreg), false, false);
        lreg = __int_as_float(sw.x) + __int_as_float(sw.y);
    }
    float inv = 1.0f / lreg;
    float* obase = out + (size_t)q * DMODEL + h * HDIM + l5 * 4;
    #pragma unroll
    for (int dt = 0; dt < 2; ++dt)
        #pragma unroll
        for (int g = 0; g < 4; ++g) {
            f32x4 o4;
            o4[0] = of[dt][g * 4 + 0] * inv;
            o4[1] = of[dt][g * 4 + 1] * inv;
            o4[2] = of[dt][g * 4 + 2] * inv;
            o4[3] = of[dt][g * 4 + 3] * inv;
            *reinterpret_cast<f32x4*>(obase + dt * 32 + g * 8) = o4;
        }
}

extern "C" void kernel_launch(void* const* d_in, const int* in_sizes, int n_in,
                              void* d_out, int out_size, void* d_ws, size_t ws_size,
                              hipStream_t stream) {
    (void)in_sizes; (void)n_in; (void)out_size; (void)ws_size;
    const float* q  = (const float*)d_in[0];
    const float* k  = (const float*)d_in[1];
    const float* v  = (const float*)d_in[2];
    // d_in[3] = mask: tril(ones) -> causal, applied analytically
    const float* Wq = (const float*)d_in[4];
    const float* Wk = (const float*)d_in[5];
    const float* Wv = (const float*)d_in[6];

    unsigned short* qh  = (unsigned short*)d_ws;                 // 8 MB
    unsigned short* kh  = qh + (size_t)NHEADS * SEQ * HDIM;      // 8 MB
    unsigned short* vht = kh + (size_t)NHEADS * SEQ * HDIM;      // 8 MB
    float* out = (float*)d_out;

    dim3 g1(SEQ / 128, DMODEL / 128, 3);
    proj_rope_kernel<<<g1, 256, 0, stream>>>(q, k, v, Wq, Wk, Wv, qh, kh, vht);

    attn_kernel<<<dim3(2048), 64, 0, stream>>>(qh, kh, vht, out);
}